// Round 9
// baseline (1173.570 us; speedup 1.0000x reference)
//
#include <hip/hip_runtime.h>
#include <stdint.h>
#include <stddef.h>

typedef float f32x16 __attribute__((ext_vector_type(16)));
typedef int i32x8 __attribute__((ext_vector_type(8)));

union Frag32 { long l[4]; i32x8 v; };  // 32 bytes = one scaled-MFMA operand/lane

// ---------------------------------------------------------------------------
// Quantized operands live in an "LDS-image" layout: 8 KB slots; slot
// s = blk*(K/32) + ksl holds rows [blk*256..+256) x k-bytes [ksl*32..+32).
// Swizzle (16B granular): logical L = row*32 + kkb stored at physical
// P = L ^ (((row>>2)&1)<<4).
//
// R9 GEMM: A via LDS ring-4 (linear gl_lds staging + swizzled b128 reads,
// R3-R8-verified bank behavior); B read DIRECTLY from the global image into
// registers (VMEM/L1/L2 path — idle while LDS saturates). Per-CU-phase LDS
// traffic drops 160KB -> 80KB; MFMA (1100cy) becomes the tallest pipe.
// XCD-chunked n-major block swizzle keeps each XCD's ~32 co-resident blocks
// on ONE B panel -> B slice is L2-resident.
//
// GEMM inner op: mfma_scale_f32_32x32x64_f8f6f4 with unit E8M0 scales
// (0x7F/byte -> x1.0): bit-exact fp8 matmul at the 2x MX rate.
//
// Workspace layout (bytes):
//   [0..7]    : two u32 atomic absmax slots (w_absmax_bits, x_absmax_bits)
//   [256 .. 256+M*K)            : x_q  LDS-image slots (32 MB)
//   [256+M*K .. 256+M*K+N*K)    : w_qT LDS-image slots (64 MB)
// ---------------------------------------------------------------------------

__global__ void absmax_kernel(const float4* __restrict__ x, size_t n4,
                              unsigned int* __restrict__ out) {
  size_t idx = ((size_t)blockIdx.x * blockDim.x + threadIdx.x) * 2;
  size_t stride = (size_t)gridDim.x * blockDim.x * 2;
  float m0 = 0.f, m1 = 0.f;
  for (size_t i = idx; i < n4; i += stride) {
    float4 v = x[i];
    float4 u = x[i + 1];  // n4 is even for both inputs
    m0 = fmaxf(m0, fmaxf(fmaxf(fabsf(v.x), fabsf(v.y)),
                         fmaxf(fabsf(v.z), fabsf(v.w))));
    m1 = fmaxf(m1, fmaxf(fmaxf(fabsf(u.x), fabsf(u.y)),
                         fmaxf(fabsf(u.z), fabsf(u.w))));
  }
  float m = fmaxf(m0, m1);
#pragma unroll
  for (int off = 32; off > 0; off >>= 1)
    m = fmaxf(m, __shfl_xor(m, off));
  if ((threadIdx.x & 63) == 0)
    atomicMax(out, __float_as_uint(m));  // all values >= 0: uint order == float order
}

// x [M][K] f32 -> LDS-image slots. One thread = one 16B logical chunk.
__global__ void quantize_x_kernel(const float4* __restrict__ x,
                                  uint8_t* __restrict__ xq,
                                  const unsigned int* __restrict__ amax,
                                  int K, int n_chunks) {
  const float x_scale = __uint_as_float(amax[1]) / 448.0f;
  const float inv = 1.0f / x_scale;
  const int kslots = K >> 5;
  int idx = blockIdx.x * blockDim.x + threadIdx.x;
  const int stride = gridDim.x * blockDim.x;
  for (; idx < n_chunks; idx += stride) {
    const int slot = idx >> 9;        // 512 chunks of 16B per 8KB slot
    const int p16 = idx & 511;
    const int row = p16 >> 1;
    const int kkb0 = (p16 & 1) << 4;
    const int mblk = slot / kslots;
    const int ksl = slot - mblk * kslots;
    const size_t f4 = ((size_t)(mblk * 256 + row) * K + ksl * 32 + kkb0) >> 2;
    const float4 v0 = x[f4 + 0], v1 = x[f4 + 1], v2 = x[f4 + 2], v3 = x[f4 + 3];
    uint32_t c0 = __builtin_amdgcn_cvt_pk_fp8_f32(v0.x * inv, v0.y * inv, 0, false);
    c0 = __builtin_amdgcn_cvt_pk_fp8_f32(v0.z * inv, v0.w * inv, c0, true);
    uint32_t c1 = __builtin_amdgcn_cvt_pk_fp8_f32(v1.x * inv, v1.y * inv, 0, false);
    c1 = __builtin_amdgcn_cvt_pk_fp8_f32(v1.z * inv, v1.w * inv, c1, true);
    uint32_t c2 = __builtin_amdgcn_cvt_pk_fp8_f32(v2.x * inv, v2.y * inv, 0, false);
    c2 = __builtin_amdgcn_cvt_pk_fp8_f32(v2.z * inv, v2.w * inv, c2, true);
    uint32_t c3 = __builtin_amdgcn_cvt_pk_fp8_f32(v3.x * inv, v3.y * inv, 0, false);
    c3 = __builtin_amdgcn_cvt_pk_fp8_f32(v3.z * inv, v3.w * inv, c3, true);
    const int paddr = (row * 32 + kkb0) ^ (((row >> 2) & 1) << 4);
    uint4 o;
    o.x = c0; o.y = c1; o.z = c2; o.w = c3;
    *(uint4*)(xq + (size_t)slot * 8192 + paddr) = o;
  }
}

// w [K][N] f32 -> w^T LDS-image slots. 64n x 128k tile per block.
__global__ void quantize_wT_kernel(const float* __restrict__ w,
                                   uint8_t* __restrict__ wqt,
                                   const unsigned int* __restrict__ amax,
                                   int N, int K) {
  __shared__ float tileF[64][129];
  const float w_scale = __uint_as_float(amax[0]) / 448.0f;
  const float inv = 1.0f / w_scale;
  const int tn = blockIdx.x;   // 64-wide n tile
  const int tk = blockIdx.y;   // 128-wide k tile
  const int t = threadIdx.x;
  {
    const int nn4 = t & 15;
    const int kk0 = t >> 4;    // 0..15
#pragma unroll
    for (int i = 0; i < 8; ++i) {
      const int kk = kk0 + i * 16;  // 0..127
      const float4 v =
          *(const float4*)&w[(size_t)(tk * 128 + kk) * N + tn * 64 + nn4 * 4];
      tileF[nn4 * 4 + 0][kk] = v.x;
      tileF[nn4 * 4 + 1][kk] = v.y;
      tileF[nn4 * 4 + 2][kk] = v.z;
      tileF[nn4 * 4 + 3][kk] = v.w;
    }
  }
  __syncthreads();
  {
    const int n = t & 63;
    const int c = t >> 6;      // 0..3: which 32-k chunk (wave-uniform)
    unsigned long long q[4];
#pragma unroll
    for (int cc = 0; cc < 4; ++cc) {
      const float4 u0 = *(const float4*)&tileF[n][c * 32 + cc * 8];
      const float4 u1 = *(const float4*)&tileF[n][c * 32 + cc * 8 + 4];
      uint32_t lo = __builtin_amdgcn_cvt_pk_fp8_f32(u0.x * inv, u0.y * inv, 0, false);
      lo = __builtin_amdgcn_cvt_pk_fp8_f32(u0.z * inv, u0.w * inv, lo, true);
      uint32_t hi = __builtin_amdgcn_cvt_pk_fp8_f32(u1.x * inv, u1.y * inv, 0, false);
      hi = __builtin_amdgcn_cvt_pk_fp8_f32(u1.z * inv, u1.w * inv, hi, true);
      q[cc] = (unsigned long long)lo | ((unsigned long long)hi << 32);
    }
    const int n_g = tn * 64 + n;
    const int k0g = tk * 128 + c * 32;
    const size_t slot = (size_t)(n_g >> 8) * (K >> 5) + (k0g >> 5);
    const int row = n_g & 255;
    const int bit = (row >> 2) & 1;
    uint8_t* pbase = wqt + slot * 8192 + row * 32;
    ulonglong2 s0, s1;
    s0.x = q[0]; s0.y = q[1];
    s1.x = q[2]; s1.y = q[3];
    *(ulonglong2*)(pbase + (bit << 4)) = s0;
    *(ulonglong2*)(pbase + ((bit ^ 1) << 4)) = s1;
  }
}

// ---------------------------------------------------------------------------
// fp8 GEMM, 256x256 tile, 16 waves (4x4), 64x64/wave, 32x32x64 MX MFMA.
// A: LDS ring-4, lead-2 gl_lds staging, b128 swizzled reads.
// B: direct global->register loads (VMEM path), coalesced 1KB segments.
// Exactly 5 VMEM ops/phase (4 B + 1 A-stage): vmcnt(1) before MFMA waits
// B(p) + Astage(p+1), leaves Astage(p+2) in flight. Barrier per phase.
// ---------------------------------------------------------------------------
#define T_BM 256
#define T_BN 256
#define UNIT_SCALE 0x7F7F7F7F

__device__ __forceinline__ void gl_lds16(const uint8_t* g, uint8_t* lds) {
  __builtin_amdgcn_global_load_lds(
      (const __attribute__((address_space(1))) void*)g,
      (__attribute__((address_space(3))) void*)lds, 16, 0, 0);
}

__global__ __launch_bounds__(1024, 4) void gemm_fp8_mx(
    const uint8_t* __restrict__ Aq, const uint8_t* __restrict__ BqT,
    const float* __restrict__ bias, const unsigned int* __restrict__ amax,
    float* __restrict__ C, int M, int N, int K) {
  extern __shared__ uint8_t smem[];
  uint8_t* const Ar = smem;            // A ring: 4 slices x 16384 = 64 KB

  // XCD-chunked swizzle, n-major-slow: XCD x runs a contiguous wg range =
  // all 32 m-tiles x 8 n-tiles -> co-resident blocks share one B panel.
  const int nwg = gridDim.x;           // 2048, %8 == 0
  const int cpx = nwg >> 3;
  const int bid = blockIdx.x;
  const int wg = (bid & 7) * cpx + (bid >> 3);
  const int ntm = M / T_BM;            // 32 (power of 2)
  const int tm = wg & (ntm - 1);
  const int tn = wg / ntm;
  const int m0 = tm * T_BM;
  const int n0 = tn * T_BN;

  const int tid = threadIdx.x;
  const int w = tid >> 6;      // wave 0..15
  const int l = tid & 63;
  const int wr = w >> 2;       // 0..3  (M quarter)
  const int wc = w & 3;        // 0..3  (N quarter)

  const int kslots = K >> 5;

  // A staging: wave w stages bytes [w*1024, +1024) of each 16KB slice.
  const int soff = w * 1024 + l * 16;
  const uint8_t* a_src = Aq + (size_t)(m0 >> 8) * kslots * 8192 + soff;

  // fragment offsets: lane half h = l>>5 -> slot h within the slice.
  const int h = l >> 5;
  const int rl = l & 31;
  int aoff[2][2], boff[2][2];
#pragma unroll
  for (int mt = 0; mt < 2; ++mt) {
    const int ra = wr * 64 + mt * 32 + rl;
    const int rb = wc * 64 + mt * 32 + rl;
#pragma unroll
    for (int c = 0; c < 2; ++c) {
      aoff[mt][c] = h * 8192 + ra * 32 + ((c ^ ((ra >> 2) & 1)) << 4);
      boff[mt][c] = h * 8192 + rb * 32 + ((c ^ ((rb >> 2) & 1)) << 4);
    }
  }
  // B base for this block's n-panel (global image, read directly)
  const uint8_t* b_blk = BqT + (size_t)(n0 >> 8) * kslots * 8192;

  f32x16 acc[2][2];
#pragma unroll
  for (int i = 0; i < 2; ++i)
#pragma unroll
    for (int j = 0; j < 2; ++j) acc[i][j] = 0.f;

  const int NP = K >> 6;  // 64 phases (one 16 KB K-slice each)

  // prologue: stage A slices 0,1 into ring slots 0,1
  gl_lds16(a_src, Ar + soff);
  gl_lds16(a_src + 16384, Ar + 16384 + soff);
  asm volatile("s_waitcnt vmcnt(1)" ::: "memory");  // slice 0 landed
  __builtin_amdgcn_s_barrier();
  // invariant entering each phase: exactly 1 VMEM outstanding (next A-stage)

  for (int p = 0; p < NP; ++p) {
    // 1. B(p) fragments: direct global loads (textually first -> oldest)
    const uint8_t* bp = b_blk + (size_t)p * 16384;
    Frag32 bf[2];
#pragma unroll
    for (int mt = 0; mt < 2; ++mt) {
      ulonglong2 t0 = *(const ulonglong2*)(bp + boff[mt][0]);
      ulonglong2 t1 = *(const ulonglong2*)(bp + boff[mt][1]);
      bf[mt].l[0] = (long)t0.x; bf[mt].l[1] = (long)t0.y;
      bf[mt].l[2] = (long)t1.x; bf[mt].l[3] = (long)t1.y;
    }

    // 2. stage A slice p+2 into ring slot (p+2)&3 (tail: dead slot, any data)
    const int ss = (p + 2 < NP) ? (p + 2) : (NP - 1);
    gl_lds16(a_src + (size_t)ss * 16384, Ar + ((p + 2) & 3) * 16384 + soff);

    // 3. A fragments from ring slot p&3 (compiler-managed lgkmcnt)
    const uint8_t* Asl = Ar + (p & 3) * 16384;
    Frag32 af[2];
#pragma unroll
    for (int mt = 0; mt < 2; ++mt) {
      ulonglong2 t0 = *(const ulonglong2*)(Asl + aoff[mt][0]);
      ulonglong2 t1 = *(const ulonglong2*)(Asl + aoff[mt][1]);
      af[mt].l[0] = (long)t0.x; af[mt].l[1] = (long)t0.y;
      af[mt].l[2] = (long)t1.x; af[mt].l[3] = (long)t1.y;
    }

    // 4. counted wait: B(p) + Astage(p+1) complete; Astage(p+2) stays in flight
    asm volatile("s_waitcnt vmcnt(1)" ::: "memory");

    // 5. 4 MFMAs (64x64 per wave)
    __builtin_amdgcn_s_setprio(1);
    acc[0][0] = __builtin_amdgcn_mfma_scale_f32_32x32x64_f8f6f4(
        af[0].v, bf[0].v, acc[0][0], 0, 0, 0, UNIT_SCALE, 0, UNIT_SCALE);
    acc[1][0] = __builtin_amdgcn_mfma_scale_f32_32x32x64_f8f6f4(
        af[1].v, bf[0].v, acc[1][0], 0, 0, 0, UNIT_SCALE, 0, UNIT_SCALE);
    acc[0][1] = __builtin_amdgcn_mfma_scale_f32_32x32x64_f8f6f4(
        af[0].v, bf[1].v, acc[0][1], 0, 0, 0, UNIT_SCALE, 0, UNIT_SCALE);
    acc[1][1] = __builtin_amdgcn_mfma_scale_f32_32x32x64_f8f6f4(
        af[1].v, bf[1].v, acc[1][1], 0, 0, 0, UNIT_SCALE, 0, UNIT_SCALE);
    __builtin_amdgcn_s_setprio(0);

    __builtin_amdgcn_s_barrier();
  }
  asm volatile("s_waitcnt vmcnt(0)" ::: "memory");  // drain tail stage

  // epilogue: C = acc * (x_scale*w_scale) + bias
  // 32x32 C/D layout: col = l&31, row = (r&3) + 8*(r>>2) + 4*(l>>5)
  const float x_scale = __uint_as_float(amax[1]) / 448.0f;
  const float w_scale = __uint_as_float(amax[0]) / 448.0f;
  const float s = x_scale * w_scale;
  const int colb = n0 + wc * 64 + rl;
  const int rowb = m0 + wr * 64 + 4 * h;
#pragma unroll
  for (int nt = 0; nt < 2; ++nt) {
    const int col = colb + nt * 32;
    const float bv = bias[col];
#pragma unroll
    for (int mt = 0; mt < 2; ++mt) {
#pragma unroll
      for (int r = 0; r < 16; ++r) {
        const int row = rowb + mt * 32 + (r & 3) + 8 * (r >> 2);
        C[(size_t)row * N + col] = acc[mt][nt][r] * s + bv;
      }
    }
  }
}

extern "C" void kernel_launch(void* const* d_in, const int* in_sizes, int n_in,
                              void* d_out, int out_size, void* d_ws, size_t ws_size,
                              hipStream_t stream) {
  const float* inp = (const float*)d_in[0];
  const float* weight = (const float*)d_in[1];
  const float* bias = (const float*)d_in[2];
  float* out = (float*)d_out;

  const int N = in_sizes[2];                 // 16384
  const int K = in_sizes[1] / N;             // 4096
  const int M = in_sizes[0] / K;             // 8192

  uint8_t* ws = (uint8_t*)d_ws;
  unsigned int* amax = (unsigned int*)ws;
  uint8_t* xq = ws + 256;
  uint8_t* wqt = ws + 256 + (size_t)M * K;

  hipMemsetAsync(d_ws, 0, 8, stream);  // zero the two atomic absmax slots

  absmax_kernel<<<2048, 256, 0, stream>>>((const float4*)weight,
                                          (size_t)K * N / 4, amax + 0);
  absmax_kernel<<<2048, 256, 0, stream>>>((const float4*)inp,
                                          (size_t)M * K / 4, amax + 1);

  quantize_x_kernel<<<4096, 256, 0, stream>>>((const float4*)inp, xq, amax,
                                              K, M * K / 16);
  quantize_wT_kernel<<<dim3(N / 64, K / 128), 256, 0, stream>>>(weight, wqt,
                                                                amax, N, K);

  gemm_fp8_mx<<<(M / T_BM) * (N / T_BN), 1024, 65536, stream>>>(
      xq, wqt, bias, amax, out, M, N, K);
}

// Round 10
// 952.508 us; speedup vs baseline: 1.2321x; 1.2321x over previous
//
#include <hip/hip_runtime.h>
#include <stdint.h>
#include <stddef.h>

typedef float f32x16 __attribute__((ext_vector_type(16)));
typedef int i32x8 __attribute__((ext_vector_type(8)));

union Frag32 { long l[4]; i32x8 v; };  // 32 bytes = one scaled-MFMA operand/lane

// ---------------------------------------------------------------------------
// Quantized operands live in an "LDS-image" layout: 8 KB slots; slot
// s = blk*(K/32) + ksl holds rows [blk*256..+256) x k-bytes [ksl*32..+32).
// Swizzle (16B granular): logical L = row*32 + kkb stored at physical
// P = L ^ (((row>>2)&1)<<4).
//
// R10 GEMM: 128x256 tile, 512 threads (8 waves of 64x64), ring-3 LDS
// (72 KB) -> TWO independent blocks per CU (same 4 waves/SIMD as R6 but
// two decorrelated barrier domains; m97's implicit cross-block overlap).
// Counted vmcnt(3): stage(p+2) flies 2 full phases; single barrier/phase.
// Fragment reads: b128 at P = h*half + row*32 + ((c^((row>>2)&1))<<4) --
// 8 accesses per bank-quad = the b128 floor (R3-R8-verified swizzle).
//
// GEMM inner op: mfma_scale_f32_32x32x64_f8f6f4 with unit E8M0 scales
// (0x7F/byte -> x1.0): bit-exact fp8 matmul at the 2x MX rate.
//
// Workspace layout (bytes):
//   [0..7]    : two u32 atomic absmax slots (w_absmax_bits, x_absmax_bits)
//   [256 .. 256+M*K)            : x_q  LDS-image slots (32 MB)
//   [256+M*K .. 256+M*K+N*K)    : w_qT LDS-image slots (64 MB)
// ---------------------------------------------------------------------------

__global__ void absmax_kernel(const float4* __restrict__ x, size_t n4,
                              unsigned int* __restrict__ out) {
  size_t idx = ((size_t)blockIdx.x * blockDim.x + threadIdx.x) * 2;
  size_t stride = (size_t)gridDim.x * blockDim.x * 2;
  float m0 = 0.f, m1 = 0.f;
  for (size_t i = idx; i < n4; i += stride) {
    float4 v = x[i];
    float4 u = x[i + 1];  // n4 is even for both inputs
    m0 = fmaxf(m0, fmaxf(fmaxf(fabsf(v.x), fabsf(v.y)),
                         fmaxf(fabsf(v.z), fabsf(v.w))));
    m1 = fmaxf(m1, fmaxf(fmaxf(fabsf(u.x), fabsf(u.y)),
                         fmaxf(fabsf(u.z), fabsf(u.w))));
  }
  float m = fmaxf(m0, m1);
#pragma unroll
  for (int off = 32; off > 0; off >>= 1)
    m = fmaxf(m, __shfl_xor(m, off));
  if ((threadIdx.x & 63) == 0)
    atomicMax(out, __float_as_uint(m));  // all values >= 0: uint order == float order
}

// x [M][K] f32 -> LDS-image slots. One thread = one 16B logical chunk.
__global__ void quantize_x_kernel(const float4* __restrict__ x,
                                  uint8_t* __restrict__ xq,
                                  const unsigned int* __restrict__ amax,
                                  int K, int n_chunks) {
  const float x_scale = __uint_as_float(amax[1]) / 448.0f;
  const float inv = 1.0f / x_scale;
  const int kslots = K >> 5;
  int idx = blockIdx.x * blockDim.x + threadIdx.x;
  const int stride = gridDim.x * blockDim.x;
  for (; idx < n_chunks; idx += stride) {
    const int slot = idx >> 9;        // 512 chunks of 16B per 8KB slot
    const int p16 = idx & 511;
    const int row = p16 >> 1;
    const int kkb0 = (p16 & 1) << 4;
    const int mblk = slot / kslots;
    const int ksl = slot - mblk * kslots;
    const size_t f4 = ((size_t)(mblk * 256 + row) * K + ksl * 32 + kkb0) >> 2;
    const float4 v0 = x[f4 + 0], v1 = x[f4 + 1], v2 = x[f4 + 2], v3 = x[f4 + 3];
    uint32_t c0 = __builtin_amdgcn_cvt_pk_fp8_f32(v0.x * inv, v0.y * inv, 0, false);
    c0 = __builtin_amdgcn_cvt_pk_fp8_f32(v0.z * inv, v0.w * inv, c0, true);
    uint32_t c1 = __builtin_amdgcn_cvt_pk_fp8_f32(v1.x * inv, v1.y * inv, 0, false);
    c1 = __builtin_amdgcn_cvt_pk_fp8_f32(v1.z * inv, v1.w * inv, c1, true);
    uint32_t c2 = __builtin_amdgcn_cvt_pk_fp8_f32(v2.x * inv, v2.y * inv, 0, false);
    c2 = __builtin_amdgcn_cvt_pk_fp8_f32(v2.z * inv, v2.w * inv, c2, true);
    uint32_t c3 = __builtin_amdgcn_cvt_pk_fp8_f32(v3.x * inv, v3.y * inv, 0, false);
    c3 = __builtin_amdgcn_cvt_pk_fp8_f32(v3.z * inv, v3.w * inv, c3, true);
    const int paddr = (row * 32 + kkb0) ^ (((row >> 2) & 1) << 4);
    uint4 o;
    o.x = c0; o.y = c1; o.z = c2; o.w = c3;
    *(uint4*)(xq + (size_t)slot * 8192 + paddr) = o;
  }
}

// w [K][N] f32 -> w^T LDS-image slots. 64n x 128k tile per block.
__global__ void quantize_wT_kernel(const float* __restrict__ w,
                                   uint8_t* __restrict__ wqt,
                                   const unsigned int* __restrict__ amax,
                                   int N, int K) {
  __shared__ float tileF[64][129];
  const float w_scale = __uint_as_float(amax[0]) / 448.0f;
  const float inv = 1.0f / w_scale;
  const int tn = blockIdx.x;   // 64-wide n tile
  const int tk = blockIdx.y;   // 128-wide k tile
  const int t = threadIdx.x;
  {
    const int nn4 = t & 15;
    const int kk0 = t >> 4;    // 0..15
#pragma unroll
    for (int i = 0; i < 8; ++i) {
      const int kk = kk0 + i * 16;  // 0..127
      const float4 v =
          *(const float4*)&w[(size_t)(tk * 128 + kk) * N + tn * 64 + nn4 * 4];
      tileF[nn4 * 4 + 0][kk] = v.x;
      tileF[nn4 * 4 + 1][kk] = v.y;
      tileF[nn4 * 4 + 2][kk] = v.z;
      tileF[nn4 * 4 + 3][kk] = v.w;
    }
  }
  __syncthreads();
  {
    const int n = t & 63;
    const int c = t >> 6;      // 0..3: which 32-k chunk (wave-uniform)
    unsigned long long q[4];
#pragma unroll
    for (int cc = 0; cc < 4; ++cc) {
      const float4 u0 = *(const float4*)&tileF[n][c * 32 + cc * 8];
      const float4 u1 = *(const float4*)&tileF[n][c * 32 + cc * 8 + 4];
      uint32_t lo = __builtin_amdgcn_cvt_pk_fp8_f32(u0.x * inv, u0.y * inv, 0, false);
      lo = __builtin_amdgcn_cvt_pk_fp8_f32(u0.z * inv, u0.w * inv, lo, true);
      uint32_t hi = __builtin_amdgcn_cvt_pk_fp8_f32(u1.x * inv, u1.y * inv, 0, false);
      hi = __builtin_amdgcn_cvt_pk_fp8_f32(u1.z * inv, u1.w * inv, hi, true);
      q[cc] = (unsigned long long)lo | ((unsigned long long)hi << 32);
    }
    const int n_g = tn * 64 + n;
    const int k0g = tk * 128 + c * 32;
    const size_t slot = (size_t)(n_g >> 8) * (K >> 5) + (k0g >> 5);
    const int row = n_g & 255;
    const int bit = (row >> 2) & 1;
    uint8_t* pbase = wqt + slot * 8192 + row * 32;
    ulonglong2 s0, s1;
    s0.x = q[0]; s0.y = q[1];
    s1.x = q[2]; s1.y = q[3];
    *(ulonglong2*)(pbase + (bit << 4)) = s0;
    *(ulonglong2*)(pbase + ((bit ^ 1) << 4)) = s1;
  }
}

// ---------------------------------------------------------------------------
// fp8 GEMM, 128x256 tile, 8 waves (2Mx4N of 64x64), 32x32x64 MX MFMA.
// Ring-3 (A 3x8KB + B 3x16KB = 72 KB) -> 2 blocks/CU. Per phase:
// stage slice p+2 (3 gl_lds) -> read frags p (8 b128) -> 4 MFMA ->
// vmcnt(3) -> barrier.
// ---------------------------------------------------------------------------
#define T_BM 128
#define T_BN 256
#define UNIT_SCALE 0x7F7F7F7F

__device__ __forceinline__ void gl_lds16(const uint8_t* g, uint8_t* lds) {
  __builtin_amdgcn_global_load_lds(
      (const __attribute__((address_space(1))) void*)g,
      (__attribute__((address_space(3))) void*)lds, 16, 0, 0);
}

__global__ __launch_bounds__(512, 4) void gemm_fp8_mx(
    const uint8_t* __restrict__ Aq, const uint8_t* __restrict__ BqT,
    const float* __restrict__ bias, const unsigned int* __restrict__ amax,
    float* __restrict__ C, int M, int N, int K) {
  extern __shared__ uint8_t smem[];
  // layout: A ring 3 x 8192 @ 0; B ring 3 x 16384 @ 24576. total 73728.

  const int ntn = N / T_BN;            // 64
  const int bid = blockIdx.x;
  const int m0 = (bid / ntn) * T_BM;
  const int n0 = (bid % ntn) * T_BN;

  const int tid = threadIdx.x;
  const int w = tid >> 6;      // wave 0..7
  const int l = tid & 63;
  const int wr = w >> 2;       // 0..1  (M half)
  const int wc = w & 3;        // 0..3  (N quarter)

  const int kslots = K >> 5;
  const int mblk = m0 >> 8;            // A image 256-row block
  const int r0 = m0 & 255;             // 0 or 128: which half of the block

  // staging sources (slice 0); advance by 16384 per phase.
  // A slice = half-slot pair: wave w stages LDS A-chunk w (1KB):
  //   h = w>>2 (slot parity), rowgroup (w&3)*32.
  const uint8_t* a_stg = Aq + ((size_t)(mblk * kslots + (w >> 2))) * 8192 +
                         r0 * 32 + (w & 3) * 1024 + l * 16;
  // B slice = full slot pair (16KB): wave w stages chunks w and w+8.
  const uint8_t* b_stg = BqT + ((size_t)((n0 >> 8) * kslots)) * 8192 +
                         w * 1024 + l * 16;
  const int a_ldst = w * 1024;         // LDS dest offsets (lane addr added via ptr)
  const int b_ldst0 = w * 1024;
  const int b_ldst1 = 8192 + w * 1024;

  // fragment-read offsets (within one ring buffer)
  const int h = l >> 5;
  const int rl = l & 31;
  int aoff[2][2], boff[2][2];
#pragma unroll
  for (int mt = 0; mt < 2; ++mt) {
    const int ra = wr * 64 + mt * 32 + rl;          // 0..127
    const int rb = wc * 64 + mt * 32 + rl;          // 0..255
#pragma unroll
    for (int c = 0; c < 2; ++c) {
      aoff[mt][c] = h * 4096 + ra * 32 + ((c ^ ((ra >> 2) & 1)) << 4);
      boff[mt][c] = h * 8192 + rb * 32 + ((c ^ ((rb >> 2) & 1)) << 4);
    }
  }

  f32x16 acc[2][2];
#pragma unroll
  for (int i = 0; i < 2; ++i)
#pragma unroll
    for (int j = 0; j < 2; ++j) acc[i][j] = 0.f;

  const int NP = K >> 6;  // 64 phases (one 64-k-byte slice each)

  // ring pointers (named rotation; no runtime-indexed arrays)
  uint8_t* aR = smem;            uint8_t* bR = smem + 24576;
  uint8_t* aM = smem + 8192;     uint8_t* bM = smem + 24576 + 16384;
  uint8_t* aS = smem + 16384;    uint8_t* bS = smem + 24576 + 32768;

  // prologue: stage slices 0,1 into ring bufs 0,1
  gl_lds16(a_stg, aR + a_ldst + l * 16);
  gl_lds16(b_stg, bR + b_ldst0 + l * 16);
  gl_lds16(b_stg + 8192, bR + b_ldst1 + l * 16);
  gl_lds16(a_stg + 16384, aM + a_ldst + l * 16);
  gl_lds16(b_stg + 16384, bM + b_ldst0 + l * 16);
  gl_lds16(b_stg + 24576, bM + b_ldst1 + l * 16);
  asm volatile("s_waitcnt vmcnt(3)" ::: "memory");  // slice 0 landed
  __builtin_amdgcn_s_barrier();
  // invariant entering phase p: stage(p+1)'s 3 loads outstanding

  for (int p = 0; p < NP; ++p) {
    // 1. stage slice p+2 into buf (p+2)%3 (tail: restage last slice - dead buf)
    const size_t ssoff = (size_t)((p + 2 < NP) ? (p + 2) : (NP - 1)) * 16384;
    gl_lds16(a_stg + ssoff, aS + a_ldst + l * 16);
    gl_lds16(b_stg + ssoff, bS + b_ldst0 + l * 16);
    gl_lds16(b_stg + ssoff + 8192, bS + b_ldst1 + l * 16);

    // 2. fragments from buf p%3 (compiler-managed lgkmcnt)
    Frag32 af[2], bf[2];
#pragma unroll
    for (int mt = 0; mt < 2; ++mt) {
      ulonglong2 t0 = *(const ulonglong2*)(aR + aoff[mt][0]);
      ulonglong2 t1 = *(const ulonglong2*)(aR + aoff[mt][1]);
      af[mt].l[0] = (long)t0.x; af[mt].l[1] = (long)t0.y;
      af[mt].l[2] = (long)t1.x; af[mt].l[3] = (long)t1.y;
      ulonglong2 u0 = *(const ulonglong2*)(bR + boff[mt][0]);
      ulonglong2 u1 = *(const ulonglong2*)(bR + boff[mt][1]);
      bf[mt].l[0] = (long)u0.x; bf[mt].l[1] = (long)u0.y;
      bf[mt].l[2] = (long)u1.x; bf[mt].l[3] = (long)u1.y;
    }

    // 3. 4 MFMAs (64x64 per wave)
    __builtin_amdgcn_s_setprio(1);
    acc[0][0] = __builtin_amdgcn_mfma_scale_f32_32x32x64_f8f6f4(
        af[0].v, bf[0].v, acc[0][0], 0, 0, 0, UNIT_SCALE, 0, UNIT_SCALE);
    acc[1][0] = __builtin_amdgcn_mfma_scale_f32_32x32x64_f8f6f4(
        af[1].v, bf[0].v, acc[1][0], 0, 0, 0, UNIT_SCALE, 0, UNIT_SCALE);
    acc[0][1] = __builtin_amdgcn_mfma_scale_f32_32x32x64_f8f6f4(
        af[0].v, bf[1].v, acc[0][1], 0, 0, 0, UNIT_SCALE, 0, UNIT_SCALE);
    acc[1][1] = __builtin_amdgcn_mfma_scale_f32_32x32x64_f8f6f4(
        af[1].v, bf[1].v, acc[1][1], 0, 0, 0, UNIT_SCALE, 0, UNIT_SCALE);
    __builtin_amdgcn_s_setprio(0);

    // 4. counted wait: stage(p+1) complete; stage(p+2) stays in flight
    asm volatile("s_waitcnt vmcnt(3)" ::: "memory");
    __builtin_amdgcn_s_barrier();

    // 5. rotate ring (read <- mid <- stage <- read)
    uint8_t* ta = aR; aR = aM; aM = aS; aS = ta;
    uint8_t* tb = bR; bR = bM; bM = bS; bS = tb;
  }
  asm volatile("s_waitcnt vmcnt(0)" ::: "memory");  // drain tail stage

  // epilogue: C = acc * (x_scale*w_scale) + bias
  // 32x32 C/D layout: col = l&31, row = (r&3) + 8*(r>>2) + 4*(l>>5)
  const float x_scale = __uint_as_float(amax[1]) / 448.0f;
  const float w_scale = __uint_as_float(amax[0]) / 448.0f;
  const float s = x_scale * w_scale;
  const int colb = n0 + wc * 64 + rl;
  const int rowb = m0 + wr * 64 + 4 * h;
#pragma unroll
  for (int nt = 0; nt < 2; ++nt) {
    const int col = colb + nt * 32;
    const float bv = bias[col];
#pragma unroll
    for (int mt = 0; mt < 2; ++mt) {
#pragma unroll
      for (int r = 0; r < 16; ++r) {
        const int row = rowb + mt * 32 + (r & 3) + 8 * (r >> 2);
        C[(size_t)row * N + col] = acc[mt][nt][r] * s + bv;
      }
    }
  }
}

extern "C" void kernel_launch(void* const* d_in, const int* in_sizes, int n_in,
                              void* d_out, int out_size, void* d_ws, size_t ws_size,
                              hipStream_t stream) {
  const float* inp = (const float*)d_in[0];
  const float* weight = (const float*)d_in[1];
  const float* bias = (const float*)d_in[2];
  float* out = (float*)d_out;

  const int N = in_sizes[2];                 // 16384
  const int K = in_sizes[1] / N;             // 4096
  const int M = in_sizes[0] / K;             // 8192

  uint8_t* ws = (uint8_t*)d_ws;
  unsigned int* amax = (unsigned int*)ws;
  uint8_t* xq = ws + 256;
  uint8_t* wqt = ws + 256 + (size_t)M * K;

  hipMemsetAsync(d_ws, 0, 8, stream);  // zero the two atomic absmax slots

  absmax_kernel<<<2048, 256, 0, stream>>>((const float4*)weight,
                                          (size_t)K * N / 4, amax + 0);
  absmax_kernel<<<2048, 256, 0, stream>>>((const float4*)inp,
                                          (size_t)M * K / 4, amax + 1);

  quantize_x_kernel<<<4096, 256, 0, stream>>>((const float4*)inp, xq, amax,
                                              K, M * K / 16);
  quantize_wT_kernel<<<dim3(N / 64, K / 128), 256, 0, stream>>>(weight, wqt,
                                                                amax, N, K);

  gemm_fp8_mx<<<(M / T_BM) * (N / T_BN), 512, 73728, stream>>>(
      xq, wqt, bias, amax, out, M, N, K);
}

// Round 11
// 884.571 us; speedup vs baseline: 1.3267x; 1.0768x over previous
//
#include <hip/hip_runtime.h>
#include <stdint.h>
#include <stddef.h>

typedef float f32x16 __attribute__((ext_vector_type(16)));
typedef int i32x8 __attribute__((ext_vector_type(8)));

union Frag32 { long l[4]; i32x8 v; };  // 32 bytes = one scaled-MFMA operand/lane

// ---------------------------------------------------------------------------
// Quantized operands live in an "LDS-image" layout: 8 KB slots; slot
// s = blk*(K/32) + ksl holds rows [blk*256..+256) x k-bytes [ksl*32..+32),
// logical L = row*32 + kkb stored at physical P = L ^ (((L>>7)&3)<<3)
// (8B-chunk 2-bit XOR; R3-R6-verified: SQ_LDS_BANK_CONFLICT == 0 with the
// b64 fragment pattern P = h*8192 + row*32 + ((j ^ ((row>>2)&3))*8)).
// GEMM stages 16 KB slices (2 slots) with LINEAR gl_lds x16 copies.
//
// R11 = R6's champion GEMM + 2D-chunked XCD swizzle: co-resident 32 blocks
// per XCD form a 4(tm) x 8(tn) rectangle -> unique staged bytes per
// XCD-phase drop 576KB -> 192KB and phase-synchronized siblings hit L2.
// (R4-R10 all converge to ~12 B/cy/CU staging supply across schedules ->
// memory-supply wall, not scheduling; this attacks the supply.)
//
// GEMM inner op: mfma_scale_f32_32x32x64_f8f6f4 with unit E8M0 scales
// (0x7F/byte -> x1.0): bit-exact fp8 matmul at the 2x MX rate.
//
// Workspace layout (bytes):
//   [0..7]    : two u32 atomic absmax slots (w_absmax_bits, x_absmax_bits)
//   [256 .. 256+M*K)            : x_q  LDS-image slots (32 MB)
//   [256+M*K .. 256+M*K+N*K)    : w_qT LDS-image slots (64 MB)
// ---------------------------------------------------------------------------

__global__ void absmax_kernel(const float4* __restrict__ x, size_t n4,
                              unsigned int* __restrict__ out) {
  size_t idx = ((size_t)blockIdx.x * blockDim.x + threadIdx.x) * 2;
  size_t stride = (size_t)gridDim.x * blockDim.x * 2;
  float m0 = 0.f, m1 = 0.f;
  for (size_t i = idx; i < n4; i += stride) {
    float4 v = x[i];
    float4 u = x[i + 1];  // n4 is even for both inputs
    m0 = fmaxf(m0, fmaxf(fmaxf(fabsf(v.x), fabsf(v.y)),
                         fmaxf(fabsf(v.z), fabsf(v.w))));
    m1 = fmaxf(m1, fmaxf(fmaxf(fabsf(u.x), fabsf(u.y)),
                         fmaxf(fabsf(u.z), fabsf(u.w))));
  }
  float m = fmaxf(m0, m1);
#pragma unroll
  for (int off = 32; off > 0; off >>= 1)
    m = fmaxf(m, __shfl_xor(m, off));
  if ((threadIdx.x & 63) == 0)
    atomicMax(out, __float_as_uint(m));  // all values >= 0: uint order == float order
}

// x [M][K] f32 -> LDS-image slots (8B-chunk swizzle: two 8B stores).
__global__ void quantize_x_kernel(const float4* __restrict__ x,
                                  uint8_t* __restrict__ xq,
                                  const unsigned int* __restrict__ amax,
                                  int K, int n_chunks) {
  const float x_scale = __uint_as_float(amax[1]) / 448.0f;
  const float inv = 1.0f / x_scale;
  const int kslots = K >> 5;
  int idx = blockIdx.x * blockDim.x + threadIdx.x;
  const int stride = gridDim.x * blockDim.x;
  for (; idx < n_chunks; idx += stride) {
    const int slot = idx >> 9;        // 512 chunks of 16B per 8KB slot
    const int p16 = idx & 511;
    const int row = p16 >> 1;
    const int kkb0 = (p16 & 1) << 4;
    const int mblk = slot / kslots;
    const int ksl = slot - mblk * kslots;
    const size_t f4 = ((size_t)(mblk * 256 + row) * K + ksl * 32 + kkb0) >> 2;
    const float4 v0 = x[f4 + 0], v1 = x[f4 + 1], v2 = x[f4 + 2], v3 = x[f4 + 3];
    uint32_t c0 = __builtin_amdgcn_cvt_pk_fp8_f32(v0.x * inv, v0.y * inv, 0, false);
    c0 = __builtin_amdgcn_cvt_pk_fp8_f32(v0.z * inv, v0.w * inv, c0, true);
    uint32_t c1 = __builtin_amdgcn_cvt_pk_fp8_f32(v1.x * inv, v1.y * inv, 0, false);
    c1 = __builtin_amdgcn_cvt_pk_fp8_f32(v1.z * inv, v1.w * inv, c1, true);
    uint32_t c2 = __builtin_amdgcn_cvt_pk_fp8_f32(v2.x * inv, v2.y * inv, 0, false);
    c2 = __builtin_amdgcn_cvt_pk_fp8_f32(v2.z * inv, v2.w * inv, c2, true);
    uint32_t c3 = __builtin_amdgcn_cvt_pk_fp8_f32(v3.x * inv, v3.y * inv, 0, false);
    c3 = __builtin_amdgcn_cvt_pk_fp8_f32(v3.z * inv, v3.w * inv, c3, true);
    const unsigned long long L0 = (unsigned long long)c0 | ((unsigned long long)c1 << 32);
    const unsigned long long L1 = (unsigned long long)c2 | ((unsigned long long)c3 << 32);
    const int Lc = row * 32 + kkb0;
    const int mask = ((row >> 2) & 3) << 3;
    const int addr0 = Lc ^ (mask & 16);
    uint8_t* p = xq + (size_t)slot * 8192;
    *(unsigned long long*)(p + addr0 + (mask & 8)) = L0;
    *(unsigned long long*)(p + addr0 + (8 ^ (mask & 8))) = L1;
  }
}

// w [K][N] f32 -> w^T LDS-image slots. 64n x 128k tile per block:
// f32 LDS tile [64][129] (conflict-free writes + b128 column reads),
// register-side 8B-chunk permute, two contiguous 16B stores.
__global__ void quantize_wT_kernel(const float* __restrict__ w,
                                   uint8_t* __restrict__ wqt,
                                   const unsigned int* __restrict__ amax,
                                   int N, int K) {
  __shared__ float tileF[64][129];
  const float w_scale = __uint_as_float(amax[0]) / 448.0f;
  const float inv = 1.0f / w_scale;
  const int tn = blockIdx.x;   // 64-wide n tile
  const int tk = blockIdx.y;   // 128-wide k tile
  const int t = threadIdx.x;
  {
    const int nn4 = t & 15;
    const int kk0 = t >> 4;    // 0..15
#pragma unroll
    for (int i = 0; i < 8; ++i) {
      const int kk = kk0 + i * 16;  // 0..127
      const float4 v =
          *(const float4*)&w[(size_t)(tk * 128 + kk) * N + tn * 64 + nn4 * 4];
      tileF[nn4 * 4 + 0][kk] = v.x;
      tileF[nn4 * 4 + 1][kk] = v.y;
      tileF[nn4 * 4 + 2][kk] = v.z;
      tileF[nn4 * 4 + 3][kk] = v.w;
    }
  }
  __syncthreads();
  {
    const int n = t & 63;
    const int c = t >> 6;      // 0..3: which 32-k chunk (wave-uniform)
    unsigned long long q[4];
#pragma unroll
    for (int cc = 0; cc < 4; ++cc) {
      const float4 u0 = *(const float4*)&tileF[n][c * 32 + cc * 8];
      const float4 u1 = *(const float4*)&tileF[n][c * 32 + cc * 8 + 4];
      uint32_t lo = __builtin_amdgcn_cvt_pk_fp8_f32(u0.x * inv, u0.y * inv, 0, false);
      lo = __builtin_amdgcn_cvt_pk_fp8_f32(u0.z * inv, u0.w * inv, lo, true);
      uint32_t hi = __builtin_amdgcn_cvt_pk_fp8_f32(u1.x * inv, u1.y * inv, 0, false);
      hi = __builtin_amdgcn_cvt_pk_fp8_f32(u1.z * inv, u1.w * inv, hi, true);
      q[cc] = (unsigned long long)lo | ((unsigned long long)hi << 32);
    }
    const int n_g = tn * 64 + n;
    const int k0g = tk * 128 + c * 32;
    const size_t slot = (size_t)(n_g >> 8) * (K >> 5) + (k0g >> 5);
    const int row = n_g & 255;
    const int m2 = (row >> 2) & 3;    // physical chunk p holds logical p^m2
    ulonglong2 s0, s1;
    s0.x = q[0 ^ m2]; s0.y = q[1 ^ m2];
    s1.x = q[2 ^ m2]; s1.y = q[3 ^ m2];
    uint8_t* pbase = wqt + slot * 8192 + row * 32;
    *(ulonglong2*)(pbase) = s0;
    *(ulonglong2*)(pbase + 16) = s1;
  }
}

// ---------------------------------------------------------------------------
// fp8 GEMM (R6 champion structure): 256x256 tile, 16 waves (4x4), 64x64 per
// wave, 32x32x64 MX MFMA, 4-slice ring, lead-2 staging, counted vmcnt(2)
// (never 0 in loop), one barrier per phase, b64 fragment reads (0-conflict).
// NEW: 2D-chunked XCD swizzle (4 tm x 8 tn co-resident rectangle per XCD).
// ---------------------------------------------------------------------------
#define T_BM 256
#define T_BN 256
#define UNIT_SCALE 0x7F7F7F7F

__device__ __forceinline__ void gl_lds16(const uint8_t* g, uint8_t* lds) {
  __builtin_amdgcn_global_load_lds(
      (const __attribute__((address_space(1))) void*)g,
      (__attribute__((address_space(3))) void*)lds, 16, 0, 0);
}

__global__ __launch_bounds__(1024, 4) void gemm_fp8_mx(
    const uint8_t* __restrict__ Aq, const uint8_t* __restrict__ BqT,
    const float* __restrict__ bias, const unsigned int* __restrict__ amax,
    float* __restrict__ C, int M, int N, int K) {
  extern __shared__ uint8_t smem[];
  uint8_t* const Ar = smem;            // 4 slices x 16384 = 64 KB
  uint8_t* const Br = smem + 65536;    // 4 slices x 16384 = 64 KB

  // 2D-chunked XCD swizzle: XCD = bid&7 (HW round-robin); within an XCD the
  // co-resident ~32 blocks (s consecutive) form a 4(tm) x 8(tn) rectangle.
  const int ntm = M / T_BM;            // 32
  const int mpx = ntm >> 3;            // 4 m-tiles per XCD
  const int bid = blockIdx.x;
  const int s = bid >> 3;
  const int tm = (bid & 7) * mpx + (s & (mpx - 1));
  const int tn = s / mpx;
  const int m0 = tm * T_BM;
  const int n0 = tn * T_BN;

  const int tid = threadIdx.x;
  const int w = tid >> 6;      // wave 0..15
  const int l = tid & 63;
  const int wr = w >> 2;       // 0..3  (M quarter)
  const int wc = w & 3;        // 0..3  (N quarter)

  const int kslots = K >> 5;

  // staging: linear contiguous copy of one 16 KB slice; wave w owns bytes
  // [w*1024, w*1024+1024), lane l the 16B at +l*16.
  const int soff = w * 1024 + l * 16;
  const uint8_t* a_src = Aq + (size_t)(m0 >> 8) * kslots * 8192 + soff;
  const uint8_t* b_src = BqT + (size_t)(n0 >> 8) * kslots * 8192 + soff;

  // fragment-read offsets: lane half h = l>>5 -> slot h within the slice.
  const int h = l >> 5;
  const int rl = l & 31;
  int aoff[2][4], boff[2][4];
#pragma unroll
  for (int mt = 0; mt < 2; ++mt) {
    const int ra = wr * 64 + mt * 32 + rl;
    const int rb = wc * 64 + mt * 32 + rl;
#pragma unroll
    for (int j = 0; j < 4; ++j) {
      aoff[mt][j] = h * 8192 + ra * 32 + ((j ^ ((ra >> 2) & 3)) * 8);
      boff[mt][j] = h * 8192 + rb * 32 + ((j ^ ((rb >> 2) & 3)) * 8);
    }
  }

  f32x16 acc[2][2];
#pragma unroll
  for (int i = 0; i < 2; ++i)
#pragma unroll
    for (int j = 0; j < 2; ++j) acc[i][j] = 0.f;

  const int NP = K >> 6;  // 64 phases (one 16 KB slice each)

  // prologue: stage slices 0,1 into ring slots 0,1
  gl_lds16(a_src, Ar + soff);
  gl_lds16(b_src, Br + soff);
  gl_lds16(a_src + 16384, Ar + 16384 + soff);
  gl_lds16(b_src + 16384, Br + 16384 + soff);
  asm volatile("s_waitcnt vmcnt(2)" ::: "memory");  // slice 0 landed
  __builtin_amdgcn_s_barrier();

  for (int p = 0; p < NP; ++p) {
    // 1. stage slice p+2 (tail: re-stage p-2 = same bytes into its dead slot)
    const int ss = (p + 2 < NP) ? (p + 2) : (p - 2);
    const int rslot = ((p + 2) & 3) * 16384;
    gl_lds16(a_src + (size_t)ss * 16384, Ar + rslot + soff);
    gl_lds16(b_src + (size_t)ss * 16384, Br + rslot + soff);

    // 2. fragments from ring slot p&3 (compiler-managed lgkmcnt)
    const uint8_t* Asl = Ar + (p & 3) * 16384;
    const uint8_t* Bsl = Br + (p & 3) * 16384;
    Frag32 af[2], bf[2];
#pragma unroll
    for (int t2 = 0; t2 < 2; ++t2)
#pragma unroll
      for (int j = 0; j < 4; ++j) {
        af[t2].l[j] = *(const long*)(Asl + aoff[t2][j]);
        bf[t2].l[j] = *(const long*)(Bsl + boff[t2][j]);
      }

    // 3. 4 MFMAs (64x64 per wave)
    __builtin_amdgcn_s_setprio(1);
    acc[0][0] = __builtin_amdgcn_mfma_scale_f32_32x32x64_f8f6f4(
        af[0].v, bf[0].v, acc[0][0], 0, 0, 0, UNIT_SCALE, 0, UNIT_SCALE);
    acc[1][0] = __builtin_amdgcn_mfma_scale_f32_32x32x64_f8f6f4(
        af[1].v, bf[0].v, acc[1][0], 0, 0, 0, UNIT_SCALE, 0, UNIT_SCALE);
    acc[0][1] = __builtin_amdgcn_mfma_scale_f32_32x32x64_f8f6f4(
        af[0].v, bf[1].v, acc[0][1], 0, 0, 0, UNIT_SCALE, 0, UNIT_SCALE);
    acc[1][1] = __builtin_amdgcn_mfma_scale_f32_32x32x64_f8f6f4(
        af[1].v, bf[1].v, acc[1][1], 0, 0, 0, UNIT_SCALE, 0, UNIT_SCALE);
    __builtin_amdgcn_s_setprio(0);

    // 4. counted wait: slice p+1 must land; slice p+2's pair stays in flight
    asm volatile("s_waitcnt vmcnt(2)" ::: "memory");
    __builtin_amdgcn_s_barrier();
  }
  asm volatile("s_waitcnt vmcnt(0)" ::: "memory");  // drain tail dummies

  // epilogue: C = acc * (x_scale*w_scale) + bias
  // 32x32 C/D layout: col = l&31, row = (r&3) + 8*(r>>2) + 4*(l>>5)
  const float x_scale = __uint_as_float(amax[1]) / 448.0f;
  const float w_scale = __uint_as_float(amax[0]) / 448.0f;
  const float sc = x_scale * w_scale;
  const int colb = n0 + wc * 64 + rl;
  const int rowb = m0 + wr * 64 + 4 * h;
#pragma unroll
  for (int nt = 0; nt < 2; ++nt) {
    const int col = colb + nt * 32;
    const float bv = bias[col];
#pragma unroll
    for (int mt = 0; mt < 2; ++mt) {
#pragma unroll
      for (int r = 0; r < 16; ++r) {
        const int row = rowb + mt * 32 + (r & 3) + 8 * (r >> 2);
        C[(size_t)row * N + col] = acc[mt][nt][r] * sc + bv;
      }
    }
  }
}

extern "C" void kernel_launch(void* const* d_in, const int* in_sizes, int n_in,
                              void* d_out, int out_size, void* d_ws, size_t ws_size,
                              hipStream_t stream) {
  const float* inp = (const float*)d_in[0];
  const float* weight = (const float*)d_in[1];
  const float* bias = (const float*)d_in[2];
  float* out = (float*)d_out;

  const int N = in_sizes[2];                 // 16384
  const int K = in_sizes[1] / N;             // 4096
  const int M = in_sizes[0] / K;             // 8192

  uint8_t* ws = (uint8_t*)d_ws;
  unsigned int* amax = (unsigned int*)ws;
  uint8_t* xq = ws + 256;
  uint8_t* wqt = ws + 256 + (size_t)M * K;

  hipMemsetAsync(d_ws, 0, 8, stream);  // zero the two atomic absmax slots

  absmax_kernel<<<2048, 256, 0, stream>>>((const float4*)weight,
                                          (size_t)K * N / 4, amax + 0);
  absmax_kernel<<<2048, 256, 0, stream>>>((const float4*)inp,
                                          (size_t)M * K / 4, amax + 1);

  quantize_x_kernel<<<4096, 256, 0, stream>>>((const float4*)inp, xq, amax,
                                              K, M * K / 16);
  quantize_wT_kernel<<<dim3(N / 64, K / 128), 256, 0, stream>>>(weight, wqt,
                                                                amax, N, K);

  gemm_fp8_mx<<<(M / T_BM) * (N / T_BN), 1024, 131072, stream>>>(
      xq, wqt, bias, amax, out, M, N, K);
}

// Round 12
// 861.064 us; speedup vs baseline: 1.3629x; 1.0273x over previous
//
#include <hip/hip_runtime.h>
#include <stdint.h>
#include <stddef.h>

typedef float f32x16 __attribute__((ext_vector_type(16)));
typedef int i32x8 __attribute__((ext_vector_type(8)));

union Frag32 { long l[4]; i32x8 v; };  // 32 bytes = one scaled-MFMA operand/lane

// ---------------------------------------------------------------------------
// Quantized operands live in an "LDS-image" layout: 8 KB slots; slot
// s = blk*(K/32) + ksl holds rows [blk*256..+256) x k-bytes [ksl*32..+32),
// logical L = row*32 + kkb stored at physical P = L ^ (((L>>7)&3)<<3)
// (8B-chunk 2-bit XOR; R3-R6-verified: SQ_LDS_BANK_CONFLICT == 0 with the
// b64 fragment pattern P = h*8192 + row*32 + ((j ^ ((row>>2)&3))*8)).
//
// GEMM (R6/R11 champion, unchanged): 256x256 tile, 16 waves of 64x64,
// 32x32x64 MX MFMA (unit E8M0 scales -> bit-exact fp8 at 2x rate), 4-slice
// ring, lead-2 gl_lds staging, counted vmcnt(2), one barrier/phase.
// Model: per CU-phase, LDS pipe moves 128KB frag reads + 32KB staging
// writes at ~64 B/cy -> 2560 cy vs measured wall 2686 cy: 95% LDS-pipe-
// saturated. This round leaves the GEMM alone and attacks pre-kernel time
// (311 us vs ~158 ideal): fused absmax (1 launch), division->shift in
// quantize_x, 5 dispatches total.
//
// Workspace layout (bytes):
//   [0..7]    : two u32 atomic absmax slots (w_absmax_bits, x_absmax_bits)
//   [256 .. 256+M*K)            : x_q  LDS-image slots (32 MB)
//   [256+M*K .. 256+M*K+N*K)    : w_qT LDS-image slots (64 MB)
// ---------------------------------------------------------------------------

__device__ __forceinline__ float max4(const float4 v) {
  return fmaxf(fmaxf(fabsf(v.x), fabsf(v.y)), fmaxf(fabsf(v.z), fabsf(v.w)));
}

// One kernel, both tensors: grid-stride scan of weight then inp, 4-way ILP.
__global__ void absmax_both_kernel(const float4* __restrict__ w, size_t wn4,
                                   const float4* __restrict__ x, size_t xn4,
                                   unsigned int* __restrict__ out) {
  const size_t tid0 = (size_t)blockIdx.x * blockDim.x + threadIdx.x;
  const size_t stride = (size_t)gridDim.x * blockDim.x * 4;
  float mw = 0.f, mx = 0.f;
  for (size_t i = tid0 * 4; i < wn4; i += stride) {
    float a = max4(w[i]), b = max4(w[i + 1]);
    float c = max4(w[i + 2]), d = max4(w[i + 3]);   // wn4 % 4 == 0
    mw = fmaxf(mw, fmaxf(fmaxf(a, b), fmaxf(c, d)));
  }
  for (size_t i = tid0 * 4; i < xn4; i += stride) {
    float a = max4(x[i]), b = max4(x[i + 1]);
    float c = max4(x[i + 2]), d = max4(x[i + 3]);   // xn4 % 4 == 0
    mx = fmaxf(mx, fmaxf(fmaxf(a, b), fmaxf(c, d)));
  }
#pragma unroll
  for (int off = 32; off > 0; off >>= 1) {
    mw = fmaxf(mw, __shfl_xor(mw, off));
    mx = fmaxf(mx, __shfl_xor(mx, off));
  }
  if ((threadIdx.x & 63) == 0) {
    atomicMax(out + 0, __float_as_uint(mw));  // vals >= 0: uint order == float
    atomicMax(out + 1, __float_as_uint(mx));
  }
}

// x [M][K] f32 -> LDS-image slots (8B-chunk swizzle: two 8B stores).
// ksh = log2(K/32): all index math is shifts/masks (no integer division).
__global__ void quantize_x_kernel(const float4* __restrict__ x,
                                  uint8_t* __restrict__ xq,
                                  const unsigned int* __restrict__ amax,
                                  int K, int ksh, int n_chunks) {
  const float x_scale = __uint_as_float(amax[1]) / 448.0f;
  const float inv = 1.0f / x_scale;
  int idx = blockIdx.x * blockDim.x + threadIdx.x;
  const int stride = gridDim.x * blockDim.x;
  for (; idx < n_chunks; idx += stride) {
    const int slot = idx >> 9;        // 512 chunks of 16B per 8KB slot
    const int p16 = idx & 511;
    const int row = p16 >> 1;
    const int kkb0 = (p16 & 1) << 4;
    const int mblk = slot >> ksh;
    const int ksl = slot & ((1 << ksh) - 1);
    const size_t f4 = ((size_t)(mblk * 256 + row) * K + ksl * 32 + kkb0) >> 2;
    const float4 v0 = x[f4 + 0], v1 = x[f4 + 1], v2 = x[f4 + 2], v3 = x[f4 + 3];
    uint32_t c0 = __builtin_amdgcn_cvt_pk_fp8_f32(v0.x * inv, v0.y * inv, 0, false);
    c0 = __builtin_amdgcn_cvt_pk_fp8_f32(v0.z * inv, v0.w * inv, c0, true);
    uint32_t c1 = __builtin_amdgcn_cvt_pk_fp8_f32(v1.x * inv, v1.y * inv, 0, false);
    c1 = __builtin_amdgcn_cvt_pk_fp8_f32(v1.z * inv, v1.w * inv, c1, true);
    uint32_t c2 = __builtin_amdgcn_cvt_pk_fp8_f32(v2.x * inv, v2.y * inv, 0, false);
    c2 = __builtin_amdgcn_cvt_pk_fp8_f32(v2.z * inv, v2.w * inv, c2, true);
    uint32_t c3 = __builtin_amdgcn_cvt_pk_fp8_f32(v3.x * inv, v3.y * inv, 0, false);
    c3 = __builtin_amdgcn_cvt_pk_fp8_f32(v3.z * inv, v3.w * inv, c3, true);
    const unsigned long long L0 = (unsigned long long)c0 | ((unsigned long long)c1 << 32);
    const unsigned long long L1 = (unsigned long long)c2 | ((unsigned long long)c3 << 32);
    const int Lc = row * 32 + kkb0;
    const int mask = ((row >> 2) & 3) << 3;
    const int addr0 = Lc ^ (mask & 16);
    uint8_t* p = xq + (size_t)slot * 8192;
    *(unsigned long long*)(p + addr0 + (mask & 8)) = L0;
    *(unsigned long long*)(p + addr0 + (8 ^ (mask & 8))) = L1;
  }
}

// w [K][N] f32 -> w^T LDS-image slots. 64n x 128k tile per block:
// f32 LDS tile [64][129] (conflict-free writes + b128 column reads),
// register-side 8B-chunk permute, two contiguous 16B stores.
__global__ void quantize_wT_kernel(const float* __restrict__ w,
                                   uint8_t* __restrict__ wqt,
                                   const unsigned int* __restrict__ amax,
                                   int N, int K) {
  __shared__ float tileF[64][129];
  const float w_scale = __uint_as_float(amax[0]) / 448.0f;
  const float inv = 1.0f / w_scale;
  const int tn = blockIdx.x;   // 64-wide n tile
  const int tk = blockIdx.y;   // 128-wide k tile
  const int t = threadIdx.x;
  {
    const int nn4 = t & 15;
    const int kk0 = t >> 4;    // 0..15
#pragma unroll
    for (int i = 0; i < 8; ++i) {
      const int kk = kk0 + i * 16;  // 0..127
      const float4 v =
          *(const float4*)&w[(size_t)(tk * 128 + kk) * N + tn * 64 + nn4 * 4];
      tileF[nn4 * 4 + 0][kk] = v.x;
      tileF[nn4 * 4 + 1][kk] = v.y;
      tileF[nn4 * 4 + 2][kk] = v.z;
      tileF[nn4 * 4 + 3][kk] = v.w;
    }
  }
  __syncthreads();
  {
    const int n = t & 63;
    const int c = t >> 6;      // 0..3: which 32-k chunk (wave-uniform)
    unsigned long long q[4];
#pragma unroll
    for (int cc = 0; cc < 4; ++cc) {
      const float4 u0 = *(const float4*)&tileF[n][c * 32 + cc * 8];
      const float4 u1 = *(const float4*)&tileF[n][c * 32 + cc * 8 + 4];
      uint32_t lo = __builtin_amdgcn_cvt_pk_fp8_f32(u0.x * inv, u0.y * inv, 0, false);
      lo = __builtin_amdgcn_cvt_pk_fp8_f32(u0.z * inv, u0.w * inv, lo, true);
      uint32_t hi = __builtin_amdgcn_cvt_pk_fp8_f32(u1.x * inv, u1.y * inv, 0, false);
      hi = __builtin_amdgcn_cvt_pk_fp8_f32(u1.z * inv, u1.w * inv, hi, true);
      q[cc] = (unsigned long long)lo | ((unsigned long long)hi << 32);
    }
    const int n_g = tn * 64 + n;
    const int k0g = tk * 128 + c * 32;
    const size_t slot = (size_t)(n_g >> 8) * (K >> 5) + (k0g >> 5);
    const int row = n_g & 255;
    const int m2 = (row >> 2) & 3;    // physical chunk p holds logical p^m2
    ulonglong2 s0, s1;
    s0.x = q[0 ^ m2]; s0.y = q[1 ^ m2];
    s1.x = q[2 ^ m2]; s1.y = q[3 ^ m2];
    uint8_t* pbase = wqt + slot * 8192 + row * 32;
    *(ulonglong2*)(pbase) = s0;
    *(ulonglong2*)(pbase + 16) = s1;
  }
}

// ---------------------------------------------------------------------------
// fp8 GEMM (champion structure, unchanged from R11).
// ---------------------------------------------------------------------------
#define T_BM 256
#define T_BN 256
#define UNIT_SCALE 0x7F7F7F7F

__device__ __forceinline__ void gl_lds16(const uint8_t* g, uint8_t* lds) {
  __builtin_amdgcn_global_load_lds(
      (const __attribute__((address_space(1))) void*)g,
      (__attribute__((address_space(3))) void*)lds, 16, 0, 0);
}

__global__ __launch_bounds__(1024, 4) void gemm_fp8_mx(
    const uint8_t* __restrict__ Aq, const uint8_t* __restrict__ BqT,
    const float* __restrict__ bias, const unsigned int* __restrict__ amax,
    float* __restrict__ C, int M, int N, int K) {
  extern __shared__ uint8_t smem[];
  uint8_t* const Ar = smem;            // 4 slices x 16384 = 64 KB
  uint8_t* const Br = smem + 65536;    // 4 slices x 16384 = 64 KB

  // 2D-chunked XCD swizzle (kept from R11; neutral-to-positive).
  const int ntm = M / T_BM;            // 32
  const int mpx = ntm >> 3;            // 4 m-tiles per XCD
  const int bid = blockIdx.x;
  const int s = bid >> 3;
  const int tm = (bid & 7) * mpx + (s & (mpx - 1));
  const int tn = s / mpx;
  const int m0 = tm * T_BM;
  const int n0 = tn * T_BN;

  const int tid = threadIdx.x;
  const int w = tid >> 6;      // wave 0..15
  const int l = tid & 63;
  const int wr = w >> 2;       // 0..3  (M quarter)
  const int wc = w & 3;        // 0..3  (N quarter)

  const int kslots = K >> 5;

  // staging: linear contiguous copy of one 16 KB slice; wave w owns bytes
  // [w*1024, w*1024+1024), lane l the 16B at +l*16.
  const int soff = w * 1024 + l * 16;
  const uint8_t* a_src = Aq + (size_t)(m0 >> 8) * kslots * 8192 + soff;
  const uint8_t* b_src = BqT + (size_t)(n0 >> 8) * kslots * 8192 + soff;

  // fragment-read offsets: lane half h = l>>5 -> slot h within the slice.
  const int h = l >> 5;
  const int rl = l & 31;
  int aoff[2][4], boff[2][4];
#pragma unroll
  for (int mt = 0; mt < 2; ++mt) {
    const int ra = wr * 64 + mt * 32 + rl;
    const int rb = wc * 64 + mt * 32 + rl;
#pragma unroll
    for (int j = 0; j < 4; ++j) {
      aoff[mt][j] = h * 8192 + ra * 32 + ((j ^ ((ra >> 2) & 3)) * 8);
      boff[mt][j] = h * 8192 + rb * 32 + ((j ^ ((rb >> 2) & 3)) * 8);
    }
  }

  f32x16 acc[2][2];
#pragma unroll
  for (int i = 0; i < 2; ++i)
#pragma unroll
    for (int j = 0; j < 2; ++j) acc[i][j] = 0.f;

  const int NP = K >> 6;  // 64 phases (one 16 KB slice each)

  // prologue: stage slices 0,1 into ring slots 0,1
  gl_lds16(a_src, Ar + soff);
  gl_lds16(b_src, Br + soff);
  gl_lds16(a_src + 16384, Ar + 16384 + soff);
  gl_lds16(b_src + 16384, Br + 16384 + soff);
  asm volatile("s_waitcnt vmcnt(2)" ::: "memory");  // slice 0 landed
  __builtin_amdgcn_s_barrier();

  for (int p = 0; p < NP; ++p) {
    // 1. stage slice p+2 (tail: re-stage p-2 = same bytes into its dead slot)
    const int ss = (p + 2 < NP) ? (p + 2) : (p - 2);
    const int rslot = ((p + 2) & 3) * 16384;
    gl_lds16(a_src + (size_t)ss * 16384, Ar + rslot + soff);
    gl_lds16(b_src + (size_t)ss * 16384, Br + rslot + soff);

    // 2. fragments from ring slot p&3 (compiler-managed lgkmcnt)
    const uint8_t* Asl = Ar + (p & 3) * 16384;
    const uint8_t* Bsl = Br + (p & 3) * 16384;
    Frag32 af[2], bf[2];
#pragma unroll
    for (int t2 = 0; t2 < 2; ++t2)
#pragma unroll
      for (int j = 0; j < 4; ++j) {
        af[t2].l[j] = *(const long*)(Asl + aoff[t2][j]);
        bf[t2].l[j] = *(const long*)(Bsl + boff[t2][j]);
      }

    // 3. 4 MFMAs (64x64 per wave)
    __builtin_amdgcn_s_setprio(1);
    acc[0][0] = __builtin_amdgcn_mfma_scale_f32_32x32x64_f8f6f4(
        af[0].v, bf[0].v, acc[0][0], 0, 0, 0, UNIT_SCALE, 0, UNIT_SCALE);
    acc[1][0] = __builtin_amdgcn_mfma_scale_f32_32x32x64_f8f6f4(
        af[1].v, bf[0].v, acc[1][0], 0, 0, 0, UNIT_SCALE, 0, UNIT_SCALE);
    acc[0][1] = __builtin_amdgcn_mfma_scale_f32_32x32x64_f8f6f4(
        af[0].v, bf[1].v, acc[0][1], 0, 0, 0, UNIT_SCALE, 0, UNIT_SCALE);
    acc[1][1] = __builtin_amdgcn_mfma_scale_f32_32x32x64_f8f6f4(
        af[1].v, bf[1].v, acc[1][1], 0, 0, 0, UNIT_SCALE, 0, UNIT_SCALE);
    __builtin_amdgcn_s_setprio(0);

    // 4. counted wait: slice p+1 must land; slice p+2's pair stays in flight
    asm volatile("s_waitcnt vmcnt(2)" ::: "memory");
    __builtin_amdgcn_s_barrier();
  }
  asm volatile("s_waitcnt vmcnt(0)" ::: "memory");  // drain tail dummies

  // epilogue: C = acc * (x_scale*w_scale) + bias
  // 32x32 C/D layout: col = l&31, row = (r&3) + 8*(r>>2) + 4*(l>>5)
  const float x_scale = __uint_as_float(amax[1]) / 448.0f;
  const float w_scale = __uint_as_float(amax[0]) / 448.0f;
  const float sc = x_scale * w_scale;
  const int colb = n0 + wc * 64 + rl;
  const int rowb = m0 + wr * 64 + 4 * h;
#pragma unroll
  for (int nt = 0; nt < 2; ++nt) {
    const int col = colb + nt * 32;
    const float bv = bias[col];
#pragma unroll
    for (int mt = 0; mt < 2; ++mt) {
#pragma unroll
      for (int r = 0; r < 16; ++r) {
        const int row = rowb + mt * 32 + (r & 3) + 8 * (r >> 2);
        C[(size_t)row * N + col] = acc[mt][nt][r] * sc + bv;
      }
    }
  }
}

extern "C" void kernel_launch(void* const* d_in, const int* in_sizes, int n_in,
                              void* d_out, int out_size, void* d_ws, size_t ws_size,
                              hipStream_t stream) {
  const float* inp = (const float*)d_in[0];
  const float* weight = (const float*)d_in[1];
  const float* bias = (const float*)d_in[2];
  float* out = (float*)d_out;

  const int N = in_sizes[2];                 // 16384
  const int K = in_sizes[1] / N;             // 4096
  const int M = in_sizes[0] / K;             // 8192

  uint8_t* ws = (uint8_t*)d_ws;
  unsigned int* amax = (unsigned int*)ws;
  uint8_t* xq = ws + 256;
  uint8_t* wqt = ws + 256 + (size_t)M * K;

  // log2(K/32) on host (K is a power of two here: 4096 -> ksh = 7)
  int ksh = 0;
  while ((1 << (ksh + 5)) < K) ++ksh;

  hipMemsetAsync(d_ws, 0, 8, stream);  // zero the two atomic absmax slots

  absmax_both_kernel<<<2048, 256, 0, stream>>>(
      (const float4*)weight, (size_t)K * N / 4,
      (const float4*)inp, (size_t)M * K / 4, amax);

  quantize_x_kernel<<<4096, 256, 0, stream>>>((const float4*)inp, xq, amax,
                                              K, ksh, M * K / 16);
  quantize_wT_kernel<<<dim3(N / 64, K / 128), 256, 0, stream>>>(weight, wqt,
                                                                amax, N, K);

  gemm_fp8_mx<<<(M / T_BM) * (N / T_BN), 1024, 131072, stream>>>(
      xq, wqt, bias, amax, out, M, N, K);
}